// Round 3
// baseline (2108.548 us; speedup 1.0000x reference)
//
#include <hip/hip_runtime.h>

typedef short v8s __attribute__((ext_vector_type(8)));
typedef float v4f __attribute__((ext_vector_type(4)));

#define T_TOK 2048
#define DD 2048
#define FF 4096
#define EE 8
#define BMG 256
#define MT_MAX 24
#define MAXROWS 6144

// workspace layout (bytes)
#define WS_COUNTS 0
#define WS_FILL   32
#define WS_ROWOFF 64
#define WS_TOPE   128
#define WS_TOPW   (WS_TOPE + T_TOK * 2 * 4)
#define WS_IDS    (WS_TOPW + T_TOK * 2 * 4)
#define WS_WTS    (WS_IDS + MAXROWS * 4)
#define WS_ZERO   (WS_WTS + MAXROWS * 4)       // 82048 bytes zeroed each launch
#define WS_H      82176ul                      // bf16 H[6144][4096]

// XOR swizzle on byte-chunk (16B) within a 128B row. Reads (16 consecutive
// rows per lg-group) => 2-way max (free). Staging writes (stride-4 rows) =>
// 4-way (1.58x on the write fraction only).
#define SWZB(r) ((((r) ^ ((r) >> 3)) & 7) << 4)
#define TADDR(r, kb) ((r) * 128 + ((kb) ^ SWZB(r)))

#define LGKM0() asm volatile("s_waitcnt lgkmcnt(0)" ::: "memory")
#define BARR()  __builtin_amdgcn_s_barrier()

static __device__ __forceinline__ short f2bf(float f) {
  return __builtin_bit_cast(short, static_cast<__bf16>(f));
}

// ---------------- router: fp32 logits, softmax, top-2 ----------------
__global__ __launch_bounds__(256) void router_k(
    const float* __restrict__ x, const float* __restrict__ gw,
    int* __restrict__ counts, int* __restrict__ tope, float* __restrict__ topw) {
  const int lane = threadIdx.x & 63;
  const int t = blockIdx.x * 4 + (threadIdx.x >> 6);
  if (t >= T_TOK) return;
  float acc[EE] = {0.f, 0.f, 0.f, 0.f, 0.f, 0.f, 0.f, 0.f};
  const float* xr = x + (size_t)t * DD;
  for (int i = 0; i < DD / 64; ++i) {
    int k = i * 64 + lane;
    float xv = xr[k];
    const v4f* g = (const v4f*)(gw + (size_t)k * EE);
    v4f g0 = g[0], g1 = g[1];
    acc[0] += xv * g0[0]; acc[1] += xv * g0[1]; acc[2] += xv * g0[2]; acc[3] += xv * g0[3];
    acc[4] += xv * g1[0]; acc[5] += xv * g1[1]; acc[6] += xv * g1[2]; acc[7] += xv * g1[3];
  }
  #pragma unroll
  for (int e = 0; e < EE; ++e) {
    #pragma unroll
    for (int off = 32; off > 0; off >>= 1) acc[e] += __shfl_xor(acc[e], off);
  }
  if (lane == 0) {
    float m = acc[0];
    #pragma unroll
    for (int e = 1; e < EE; ++e) m = fmaxf(m, acc[e]);
    float p[EE], s = 0.f;
    #pragma unroll
    for (int e = 0; e < EE; ++e) { p[e] = expf(acc[e] - m); s += p[e]; }
    float inv = 1.f / s;
    #pragma unroll
    for (int e = 0; e < EE; ++e) p[e] *= inv;
    int e1 = 0;
    #pragma unroll
    for (int e = 1; e < EE; ++e) if (p[e] > p[e1]) e1 = e;
    int e2 = (e1 == 0) ? 1 : 0;
    #pragma unroll
    for (int e = 0; e < EE; ++e) if (e != e1 && p[e] > p[e2]) e2 = e;
    tope[2 * t] = e1;  tope[2 * t + 1] = e2;
    topw[2 * t] = p[e1]; topw[2 * t + 1] = p[e2];
    atomicAdd(&counts[e1], 1);
    atomicAdd(&counts[e2], 1);
  }
}

// ---------------- per-expert padded row offsets (granularity 256) ----------------
__global__ void offsets_k(const int* __restrict__ counts, int* __restrict__ rowoff) {
  if (threadIdx.x == 0) {
    int off = 0;
    #pragma unroll
    for (int e = 0; e < EE; ++e) {
      rowoff[e] = off;
      off += ((counts[e] + BMG - 1) / BMG) * BMG;
    }
  }
}

// ---------------- scatter token ids/weights into expert-sorted slots ----------------
__global__ __launch_bounds__(256) void scatter_k(
    const int* __restrict__ tope, const float* __restrict__ topw,
    const int* __restrict__ rowoff, int* __restrict__ fill,
    int* __restrict__ ids, float* __restrict__ wts) {
  const int t = blockIdx.x * 256 + threadIdx.x;
  if (t >= T_TOK) return;
  #pragma unroll
  for (int j = 0; j < 2; ++j) {
    int e = tope[2 * t + j];
    int pos = rowoff[e] + atomicAdd(&fill[e], 1);
    ids[pos] = t;
    wts[pos] = topw[2 * t + j];
  }
}

static __device__ __forceinline__ int find_expert(
    const int* counts, const int* rowoff, int mt) {
  int expert = -1;
  #pragma unroll
  for (int e = 0; e < EE; ++e) {
    int rs = rowoff[e];
    int tl = (counts[e] + BMG - 1) >> 8;
    if (mt * BMG >= rs && mt * BMG < rs + tl * BMG) expert = e;
  }
  return expert;
}

// ======================= GEMM1: H = silu(X@W1) * (X@W3) =======================
// block: 256 token-rows x (128 f-cols x 2 mats). 8 waves, wave tile 128x64.
// A (gathered x rows) and B (w1|w3) reg-staged fp32 -> bf16 LDS, double-buffered.
// Raw s_barrier + lgkmcnt(0) only (no vmcnt drain): global loads for tile kt+2
// are issued in stage(kt) and consumed (compiler-counted vmcnt) in stage(kt+1),
// one full compute phase later.
__global__ __launch_bounds__(512, 2) void gemm1_k(
    const float* __restrict__ x, const float* __restrict__ w1,
    const float* __restrict__ w3, const int* __restrict__ counts,
    const int* __restrict__ rowoff, const int* __restrict__ ids,
    unsigned short* __restrict__ H) {
  extern __shared__ char smem[];   // 2 x 64KB: [A 256x128B | B 4x(64x128B)]
  const int nt = blockIdx.x, mt = blockIdx.y;
  const int expert = find_expert(counts, rowoff, mt);
  if (expert < 0) return;
  const int m0 = mt * BMG, n0 = nt * 128;

  const int tid = threadIdx.x;
  const int lane = tid & 63;
  const int wid = tid >> 6;
  const int lr = lane & 15, lg = lane >> 4;
  const int wr = wid >> 2;            // row half (0..1)
  const int wc = wid & 3;             // B subtile: mat*2 + colhalf
  const int c64 = (wc & 1) * 64;
  const int mat = wc >> 1;

  // A staging: thread covers row tid>>1, k-half (tid&1)*32 (128B fp32)
  const int arow = tid >> 1, ah = tid & 1;
  const float* asrc = x + (size_t)ids[m0 + arow] * DD + ah * 32;
  // B staging: 2x(256thr) cover {w1,w3} x 128f x 64k fp32
  const int smat = tid >> 8, sr = tid & 255;
  const int f4 = (sr & 31) * 4, k8 = (sr >> 5) * 8;
  const float* bsrc = (smat ? w3 : w1) + (size_t)expert * DD * FF
                      + (size_t)k8 * FF + n0 + f4;

  v4f ar[8], br[8];
  #define G1_ISSUE(KT) {                                                        \
    const float* ap_ = asrc + (size_t)(KT) * 64;                                \
    _Pragma("unroll") for (int j = 0; j < 8; ++j) ar[j] = ((const v4f*)ap_)[j]; \
    const float* bp_ = bsrc + (size_t)(KT) * 64 * FF;                           \
    _Pragma("unroll") for (int j = 0; j < 8; ++j)                               \
      br[j] = *(const v4f*)(bp_ + (size_t)j * FF); }
  #define G1_WRITE(BUF) { char* sb_ = smem + (BUF) * 65536;                     \
    _Pragma("unroll") for (int j = 0; j < 4; ++j) { v8s h_;                     \
      _Pragma("unroll") for (int q = 0; q < 4; ++q) {                           \
        h_[q] = f2bf(ar[2*j][q]); h_[q+4] = f2bf(ar[2*j+1][q]); }               \
      *(v8s*)(sb_ + TADDR(arow, ah * 64 + j * 16)) = h_; }                      \
    _Pragma("unroll") for (int c = 0; c < 4; ++c) { v8s h_;                     \
      _Pragma("unroll") for (int j = 0; j < 8; ++j) h_[j] = f2bf(br[j][c]);     \
      int fg_ = f4 + c;                                                         \
      *(v8s*)(sb_ + 32768 + (smat * 2 + (fg_ >> 6)) * 8192                      \
              + TADDR((fg_ & 63), (k8 >> 3) * 16)) = h_; } }

  v4f acc[8][4];
  #pragma unroll
  for (int i = 0; i < 8; ++i)
    #pragma unroll
    for (int j = 0; j < 4; ++j) acc[i][j] = (v4f){0.f, 0.f, 0.f, 0.f};

  G1_ISSUE(0);
  G1_WRITE(0);
  G1_ISSUE(1);
  LGKM0(); BARR();

  const int NKT = DD / 64;  // 32
  #pragma unroll 2
  for (int kt = 0; kt < NKT; ++kt) {
    const int cur = kt & 1;
    const char* cb = smem + cur * 65536;
    #pragma unroll
    for (int ks = 0; ks < 2; ++ks) {
      const int kb = ks * 64 + lg * 16;
      v8s b0 = *(const v8s*)(cb + 32768 + wc * 8192 + TADDR(0 * 16 + lr, kb));
      v8s b1 = *(const v8s*)(cb + 32768 + wc * 8192 + TADDR(1 * 16 + lr, kb));
      v8s b2 = *(const v8s*)(cb + 32768 + wc * 8192 + TADDR(2 * 16 + lr, kb));
      v8s b3 = *(const v8s*)(cb + 32768 + wc * 8192 + TADDR(3 * 16 + lr, kb));
      #pragma unroll
      for (int m = 0; m < 8; ++m) {
        v8s av = *(const v8s*)(cb + TADDR(wr * 128 + m * 16 + lr, kb));
        acc[m][0] = __builtin_amdgcn_mfma_f32_16x16x32_bf16(av, b0, acc[m][0], 0, 0, 0);
        acc[m][1] = __builtin_amdgcn_mfma_f32_16x16x32_bf16(av, b1, acc[m][1], 0, 0, 0);
        acc[m][2] = __builtin_amdgcn_mfma_f32_16x16x32_bf16(av, b2, acc[m][2], 0, 0, 0);
        acc[m][3] = __builtin_amdgcn_mfma_f32_16x16x32_bf16(av, b3, acc[m][3], 0, 0, 0);
      }
    }
    BARR();                       // all waves done READING buf[cur]
    if (kt + 1 < NKT) {
      G1_WRITE(1 - cur);          // tile kt+1 (regs issued in stage(kt-1))
      if (kt + 2 < NKT) G1_ISSUE(kt + 2);
      LGKM0();                    // ds_writes retired
    }
    BARR();                       // buf[1-cur] ready
  }

  // ---- epilogue: exchange w3 acc via LDS, silu-combine, store H (bf16) ----
  const int ebase = (wr * 2 + (wc & 1)) * 16384;
  #pragma unroll
  for (int pass = 0; pass < 2; ++pass) {
    if (mat == 1) {
      #pragma unroll
      for (int mm = 0; mm < 4; ++mm) {
        #pragma unroll
        for (int n = 0; n < 4; ++n) {
          int col = n * 16 + lr;
          *(v4f*)(smem + ebase + col * 256 + ((mm * 64 + lg * 16) ^ SWZB(col))) =
              acc[pass * 4 + mm][n];
        }
      }
    }
    LGKM0(); BARR();
    if (mat == 0) {
      #pragma unroll
      for (int mm = 0; mm < 4; ++mm) {
        int m = pass * 4 + mm;
        #pragma unroll
        for (int n = 0; n < 4; ++n) {
          int col = n * 16 + lr;
          v4f up = *(const v4f*)(smem + ebase + col * 256 +
                                 ((mm * 64 + lg * 16) ^ SWZB(col)));
          #pragma unroll
          for (int r = 0; r < 4; ++r) {
            float g = acc[m][n][r];
            float hv = (g / (1.f + expf(-g))) * up[r];
            H[(size_t)(m0 + wr * 128 + m * 16 + lg * 4 + r) * FF
              + (n0 + c64 + n * 16 + lr)] = (unsigned short)f2bf(hv);
          }
        }
      }
    }
    LGKM0(); BARR();
  }
}

// ======================= GEMM2: out[tok] += w * (H @ W2) =======================
// block: 256 rows x 256 d-cols, K split in 2 grid slices (blockIdx.z).
// A = H (bf16) reg-staged (no cvt); B = w2 fp32 reg-staged. Same pipeline.
__global__ __launch_bounds__(512, 2) void gemm2_k(
    const unsigned short* __restrict__ H, const float* __restrict__ w2,
    const int* __restrict__ counts, const int* __restrict__ rowoff,
    const int* __restrict__ ids, const float* __restrict__ wts,
    float* __restrict__ out) {
  extern __shared__ char smem[];
  const int nt = blockIdx.x, mt = blockIdx.y, ksl = blockIdx.z;
  const int expert = find_expert(counts, rowoff, mt);
  if (expert < 0) return;
  const int m0 = mt * BMG, n0 = nt * 256;
  const int kbase = ksl * 32;     // in units of BK=64 -> covers 2048 of FF

  const int tid = threadIdx.x;
  const int lane = tid & 63;
  const int wid = tid >> 6;
  const int lr = lane & 15, lg = lane >> 4;
  const int wr = wid >> 2;        // row half
  const int wq = wid & 3;         // 64-col quarter

  // A staging: thread covers row tid>>1, k-half (tid&1)*32 (64B bf16)
  const int arow = tid >> 1, ah = tid & 1;
  const unsigned short* asrc = H + (size_t)(m0 + arow) * FF
                               + (size_t)kbase * 64 + ah * 32;
  // B staging: 512 thr cover 256 d x 64 k fp32
  const int d4 = (tid & 63) * 4, k8 = (tid >> 6) * 8;
  const float* bsrc = w2 + (size_t)expert * FF * DD
                      + (size_t)(kbase * 64 + k8) * DD + n0 + d4;

  v8s ar2[4]; v4f br[8];
  #define G2_ISSUE(KT) {                                                        \
    const unsigned short* ap_ = asrc + (size_t)(KT) * 64;                       \
    _Pragma("unroll") for (int j = 0; j < 4; ++j) ar2[j] = ((const v8s*)ap_)[j];\
    const float* bp_ = bsrc + (size_t)(KT) * 64 * DD;                           \
    _Pragma("unroll") for (int j = 0; j < 8; ++j)                               \
      br[j] = *(const v4f*)(bp_ + (size_t)j * DD); }
  #define G2_WRITE(BUF) { char* sb_ = smem + (BUF) * 65536;                     \
    _Pragma("unroll") for (int j = 0; j < 4; ++j)                               \
      *(v8s*)(sb_ + TADDR(arow, ah * 64 + j * 16)) = ar2[j];                    \
    _Pragma("unroll") for (int c = 0; c < 4; ++c) { v8s h_;                     \
      _Pragma("unroll") for (int j = 0; j < 8; ++j) h_[j] = f2bf(br[j][c]);     \
      int dg_ = d4 + c;                                                         \
      *(v8s*)(sb_ + 32768 + (dg_ >> 6) * 8192                                   \
              + TADDR((dg_ & 63), (k8 >> 3) * 16)) = h_; } }

  v4f acc[8][4];
  #pragma unroll
  for (int i = 0; i < 8; ++i)
    #pragma unroll
    for (int j = 0; j < 4; ++j) acc[i][j] = (v4f){0.f, 0.f, 0.f, 0.f};

  G2_ISSUE(0);
  G2_WRITE(0);
  G2_ISSUE(1);
  LGKM0(); BARR();

  const int NKT = 32;             // 2048 K per slice
  #pragma unroll 2
  for (int kt = 0; kt < NKT; ++kt) {
    const int cur = kt & 1;
    const char* cb = smem + cur * 65536;
    #pragma unroll
    for (int ks = 0; ks < 2; ++ks) {
      const int kb = ks * 64 + lg * 16;
      v8s b0 = *(const v8s*)(cb + 32768 + wq * 8192 + TADDR(0 * 16 + lr, kb));
      v8s b1 = *(const v8s*)(cb + 32768 + wq * 8192 + TADDR(1 * 16 + lr, kb));
      v8s b2 = *(const v8s*)(cb + 32768 + wq * 8192 + TADDR(2 * 16 + lr, kb));
      v8s b3 = *(const v8s*)(cb + 32768 + wq * 8192 + TADDR(3 * 16 + lr, kb));
      #pragma unroll
      for (int m = 0; m < 8; ++m) {
        v8s av = *(const v8s*)(cb + TADDR(wr * 128 + m * 16 + lr, kb));
        acc[m][0] = __builtin_amdgcn_mfma_f32_16x16x32_bf16(av, b0, acc[m][0], 0, 0, 0);
        acc[m][1] = __builtin_amdgcn_mfma_f32_16x16x32_bf16(av, b1, acc[m][1], 0, 0, 0);
        acc[m][2] = __builtin_amdgcn_mfma_f32_16x16x32_bf16(av, b2, acc[m][2], 0, 0, 0);
        acc[m][3] = __builtin_amdgcn_mfma_f32_16x16x32_bf16(av, b3, acc[m][3], 0, 0, 0);
      }
    }
    BARR();
    if (kt + 1 < NKT) {
      G2_WRITE(1 - cur);
      if (kt + 2 < NKT) G2_ISSUE(kt + 2);
      LGKM0();
    }
    BARR();
  }

  // ---- epilogue: weighted atomic scatter-add (skip zero-weight pad rows) ----
  #pragma unroll
  for (int m = 0; m < 8; ++m) {
    #pragma unroll
    for (int r = 0; r < 4; ++r) {
      int row = m0 + wr * 128 + m * 16 + lg * 4 + r;
      float wgt = wts[row];
      if (wgt != 0.f) {
        float* orow = out + (size_t)ids[row] * DD + n0 + wq * 64 + lr;
        #pragma unroll
        for (int n = 0; n < 4; ++n)
          atomicAdd(orow + n * 16, wgt * acc[m][n][r]);
      }
    }
  }
}

extern "C" void kernel_launch(void* const* d_in, const int* in_sizes, int n_in,
                              void* d_out, int out_size, void* d_ws, size_t ws_size,
                              hipStream_t stream) {
  const float* x  = (const float*)d_in[0];
  const float* gw = (const float*)d_in[1];
  const float* w1 = (const float*)d_in[2];
  const float* w3 = (const float*)d_in[3];
  const float* w2 = (const float*)d_in[4];
  float* out = (float*)d_out;
  char* ws = (char*)d_ws;

  int*   counts = (int*)(ws + WS_COUNTS);
  int*   fill   = (int*)(ws + WS_FILL);
  int*   rowoff = (int*)(ws + WS_ROWOFF);
  int*   tope   = (int*)(ws + WS_TOPE);
  float* topw   = (float*)(ws + WS_TOPW);
  int*   ids    = (int*)(ws + WS_IDS);
  float* wts    = (float*)(ws + WS_WTS);
  unsigned short* H = (unsigned short*)(ws + WS_H);

  hipMemsetAsync(ws, 0, WS_ZERO, stream);
  hipMemsetAsync(d_out, 0, (size_t)out_size * sizeof(float), stream);

  router_k<<<T_TOK / 4, 256, 0, stream>>>(x, gw, counts, tope, topw);
  offsets_k<<<1, 64, 0, stream>>>(counts, rowoff);
  scatter_k<<<T_TOK / 256, 256, 0, stream>>>(tope, topw, rowoff, fill, ids, wts);
  gemm1_k<<<dim3(FF / 128, MT_MAX), 512, 131072, stream>>>(x, w1, w3, counts, rowoff, ids, H);
  gemm2_k<<<dim3(DD / 256, MT_MAX, 2), 512, 131072, stream>>>(H, w2, counts, rowoff, ids, wts, out);
}

// Round 4
// 550.350 us; speedup vs baseline: 3.8313x; 3.8313x over previous
//
#include <hip/hip_runtime.h>

typedef short v8s __attribute__((ext_vector_type(8)));
typedef float v4f __attribute__((ext_vector_type(4)));

#define T_TOK 2048
#define DD 2048
#define FF 4096
#define EE 8
#define BM 128
#define BN 128
#define BK 64
#define MT_MAX 40
#define MAXROWS 5120

// workspace layout (bytes)
#define WS_COUNTS 0
#define WS_FILL   32
#define WS_ROWOFF 64
#define WS_TOPE   128
#define WS_TOPW   (WS_TOPE + T_TOK * 2 * 4)   // 16512
#define WS_IDS    (WS_TOPW + T_TOK * 2 * 4)   // 32896
#define WS_WTS    (WS_IDS + MAXROWS * 4)      // 53376
#define WS_ZERO   (WS_WTS + MAXROWS * 4)      // 73856 bytes zeroed each launch
#define WS_H      73984ul                     // 256-aligned; bf16 H[5120][4096]

// XOR-swizzled byte offset within a [rows][64 bf16] LDS tile (row stride 128B).
// ((r^(r>>3))&7) spreads BOTH the stride-4 staging writes and the 16-row frag
// reads across all 8 16B slots (2 lanes/slot = free per m136). Round-1's
// (r&7) version left stride-4 writes 8-way conflicted (the measured 2.8e7).
#define SWZ(r, kb) ((r) * 128 + ((kb) ^ ((((r) ^ ((r) >> 3)) & 7) << 4)))

static __device__ __forceinline__ short f2bf(float f) {
  return __builtin_bit_cast(short, static_cast<__bf16>(f));
}

// ---------------- router: fp32 logits, softmax, top-2 ----------------
__global__ __launch_bounds__(256) void router_k(
    const float* __restrict__ x, const float* __restrict__ gw,
    int* __restrict__ counts, int* __restrict__ tope, float* __restrict__ topw) {
  const int lane = threadIdx.x & 63;
  const int t = blockIdx.x * 4 + (threadIdx.x >> 6);
  if (t >= T_TOK) return;
  float acc[EE] = {0.f, 0.f, 0.f, 0.f, 0.f, 0.f, 0.f, 0.f};
  const float* xr = x + (size_t)t * DD;
  for (int i = 0; i < DD / 64; ++i) {
    int k = i * 64 + lane;
    float xv = xr[k];
    const v4f* g = (const v4f*)(gw + (size_t)k * EE);
    v4f g0 = g[0], g1 = g[1];
    acc[0] += xv * g0[0]; acc[1] += xv * g0[1]; acc[2] += xv * g0[2]; acc[3] += xv * g0[3];
    acc[4] += xv * g1[0]; acc[5] += xv * g1[1]; acc[6] += xv * g1[2]; acc[7] += xv * g1[3];
  }
  #pragma unroll
  for (int e = 0; e < EE; ++e) {
    #pragma unroll
    for (int off = 32; off > 0; off >>= 1) acc[e] += __shfl_xor(acc[e], off);
  }
  if (lane == 0) {
    float m = acc[0];
    #pragma unroll
    for (int e = 1; e < EE; ++e) m = fmaxf(m, acc[e]);
    float p[EE], s = 0.f;
    #pragma unroll
    for (int e = 0; e < EE; ++e) { p[e] = expf(acc[e] - m); s += p[e]; }
    float inv = 1.f / s;
    #pragma unroll
    for (int e = 0; e < EE; ++e) p[e] *= inv;
    int e1 = 0;
    #pragma unroll
    for (int e = 1; e < EE; ++e) if (p[e] > p[e1]) e1 = e;
    int e2 = (e1 == 0) ? 1 : 0;
    #pragma unroll
    for (int e = 0; e < EE; ++e) if (e != e1 && p[e] > p[e2]) e2 = e;
    tope[2 * t] = e1;  tope[2 * t + 1] = e2;
    topw[2 * t] = p[e1]; topw[2 * t + 1] = p[e2];
    atomicAdd(&counts[e1], 1);
    atomicAdd(&counts[e2], 1);
  }
}

// ---------------- per-expert padded row offsets ----------------
__global__ void offsets_k(const int* __restrict__ counts, int* __restrict__ rowoff) {
  if (threadIdx.x == 0) {
    int off = 0;
    #pragma unroll
    for (int e = 0; e < EE; ++e) {
      rowoff[e] = off;
      off += ((counts[e] + BM - 1) / BM) * BM;
    }
  }
}

// ---------------- scatter token ids/weights into expert-sorted slots ----------------
__global__ __launch_bounds__(256) void scatter_k(
    const int* __restrict__ tope, const float* __restrict__ topw,
    const int* __restrict__ rowoff, int* __restrict__ fill,
    int* __restrict__ ids, float* __restrict__ wts) {
  const int t = blockIdx.x * 256 + threadIdx.x;
  if (t >= T_TOK) return;
  #pragma unroll
  for (int j = 0; j < 2; ++j) {
    int e = tope[2 * t + j];
    int pos = rowoff[e] + atomicAdd(&fill[e], 1);
    ids[pos] = t;
    wts[pos] = topw[2 * t + j];
  }
}

// ---------------- GEMM1: H = silu(X@W1) * (X@W3), bf16 out ----------------
__global__ __launch_bounds__(256, 2) void gemm1_k(
    const float* __restrict__ x, const float* __restrict__ w1,
    const float* __restrict__ w3, const int* __restrict__ counts,
    const int* __restrict__ rowoff, const int* __restrict__ ids,
    unsigned short* __restrict__ H) {
  const int nt = blockIdx.x, mt = blockIdx.y;
  int expert = -1;
  #pragma unroll
  for (int e = 0; e < EE; ++e) {
    int rs = rowoff[e];
    int tl = (counts[e] + BM - 1) / BM;
    if (mt * BM >= rs && mt * BM < rs + tl * BM) expert = e;
  }
  if (expert < 0) return;
  const int m0 = mt * BM, n0 = nt * BN;

  __shared__ unsigned short sA[BM * BK];
  __shared__ unsigned short sB0[BN * BK];
  __shared__ unsigned short sB1[BN * BK];

  const int tid = threadIdx.x;
  const int lane = tid & 63;
  const int wid = tid >> 6;
  const int wm = (wid >> 1) * 64, wn = (wid & 1) * 64;
  const int lr = lane & 15, lg = lane >> 4;

  // A staging: thread covers rows a_row0+32g, k-chunk a_kc..a_kc+8
  const int a_row0 = tid >> 3;
  const int a_kc = (tid & 7) * 8;
  const float* aptr[4];
  #pragma unroll
  for (int g = 0; g < 4; ++g)
    aptr[g] = x + (size_t)ids[m0 + a_row0 + g * 32] * DD + a_kc;

  // B staging: thread covers 4 f-rows (b_f4..+4) x 8 k (b_k8..+8), transposed into LDS
  const int b_f4 = (tid & 31) * 4;
  const int b_k8 = (tid >> 5) * 8;
  const float* wb1 = w1 + (size_t)expert * DD * FF + n0 + b_f4 + (size_t)b_k8 * FF;
  const float* wb3 = w3 + (size_t)expert * DD * FF + n0 + b_f4 + (size_t)b_k8 * FF;

  v4f acc1[4][4], acc3[4][4];
  #pragma unroll
  for (int i = 0; i < 4; ++i)
    #pragma unroll
    for (int j = 0; j < 4; ++j) {
      acc1[i][j] = (v4f){0.f, 0.f, 0.f, 0.f};
      acc3[i][j] = (v4f){0.f, 0.f, 0.f, 0.f};
    }

  for (int kt = 0; kt < DD / BK; ++kt) {
    #pragma unroll
    for (int g = 0; g < 4; ++g) {
      const float* p = aptr[g] + (size_t)kt * BK;
      v4f u0 = *(const v4f*)p;
      v4f u1 = *(const v4f*)(p + 4);
      v8s h;
      h[0] = f2bf(u0[0]); h[1] = f2bf(u0[1]); h[2] = f2bf(u0[2]); h[3] = f2bf(u0[3]);
      h[4] = f2bf(u1[0]); h[5] = f2bf(u1[1]); h[6] = f2bf(u1[2]); h[7] = f2bf(u1[3]);
      *(v8s*)((char*)sA + SWZ(a_row0 + g * 32, a_kc * 2)) = h;
    }
    {
      const float* p = wb1 + (size_t)kt * BK * FF;
      v4f r[8];
      #pragma unroll
      for (int j = 0; j < 8; ++j) r[j] = *(const v4f*)(p + (size_t)j * FF);
      #pragma unroll
      for (int c = 0; c < 4; ++c) {
        v8s h;
        #pragma unroll
        for (int j = 0; j < 8; ++j) h[j] = f2bf(r[j][c]);
        *(v8s*)((char*)sB0 + SWZ(b_f4 + c, b_k8 * 2)) = h;
      }
      p = wb3 + (size_t)kt * BK * FF;
      #pragma unroll
      for (int j = 0; j < 8; ++j) r[j] = *(const v4f*)(p + (size_t)j * FF);
      #pragma unroll
      for (int c = 0; c < 4; ++c) {
        v8s h;
        #pragma unroll
        for (int j = 0; j < 8; ++j) h[j] = f2bf(r[j][c]);
        *(v8s*)((char*)sB1 + SWZ(b_f4 + c, b_k8 * 2)) = h;
      }
    }
    __syncthreads();
    #pragma unroll
    for (int ks = 0; ks < 2; ++ks) {
      const int kb = ks * 64 + lg * 16;
      v8s a[4], b1[4], b3[4];
      #pragma unroll
      for (int m = 0; m < 4; ++m)
        a[m] = *(const v8s*)((const char*)sA + SWZ(wm + m * 16 + lr, kb));
      #pragma unroll
      for (int n = 0; n < 4; ++n) {
        b1[n] = *(const v8s*)((const char*)sB0 + SWZ(wn + n * 16 + lr, kb));
        b3[n] = *(const v8s*)((const char*)sB1 + SWZ(wn + n * 16 + lr, kb));
      }
      #pragma unroll
      for (int m = 0; m < 4; ++m)
        #pragma unroll
        for (int n = 0; n < 4; ++n) {
          acc1[m][n] = __builtin_amdgcn_mfma_f32_16x16x32_bf16(a[m], b1[n], acc1[m][n], 0, 0, 0);
          acc3[m][n] = __builtin_amdgcn_mfma_f32_16x16x32_bf16(a[m], b3[n], acc3[m][n], 0, 0, 0);
        }
    }
    __syncthreads();
  }
  #pragma unroll
  for (int m = 0; m < 4; ++m)
    #pragma unroll
    for (int n = 0; n < 4; ++n)
      #pragma unroll
      for (int r = 0; r < 4; ++r) {
        int row = wm + m * 16 + lg * 4 + r;
        int col = wn + n * 16 + lr;
        float g = acc1[m][n][r];
        float u = acc3[m][n][r];
        float hv = (g / (1.f + expf(-g))) * u;
        H[(size_t)(m0 + row) * FF + (n0 + col)] = (unsigned short)f2bf(hv);
      }
}

// ---------------- GEMM2: out[tok] += w * (H @ W2) ----------------
__global__ __launch_bounds__(256, 2) void gemm2_k(
    const unsigned short* __restrict__ H, const float* __restrict__ w2,
    const int* __restrict__ counts, const int* __restrict__ rowoff,
    const int* __restrict__ ids, const float* __restrict__ wts,
    float* __restrict__ out) {
  const int nt = blockIdx.x, mt = blockIdx.y;
  int expert = -1;
  #pragma unroll
  for (int e = 0; e < EE; ++e) {
    int rs = rowoff[e];
    int tl = (counts[e] + BM - 1) / BM;
    if (mt * BM >= rs && mt * BM < rs + tl * BM) expert = e;
  }
  if (expert < 0) return;
  const int m0 = mt * BM, n0 = nt * BN;

  __shared__ unsigned short sA[BM * BK];
  __shared__ unsigned short sB[BN * BK];

  const int tid = threadIdx.x;
  const int lane = tid & 63;
  const int wid = tid >> 6;
  const int wm = (wid >> 1) * 64, wn = (wid & 1) * 64;
  const int lr = lane & 15, lg = lane >> 4;

  const int a_row0 = tid >> 3;
  const int a_kc = (tid & 7) * 8;
  const unsigned short* ha = H + (size_t)(m0 + a_row0) * FF + a_kc;
  const int b_f4 = (tid & 31) * 4;   // output cols (d)
  const int b_k8 = (tid >> 5) * 8;   // k rows (f)
  const float* wb = w2 + (size_t)expert * FF * DD + n0 + b_f4 + (size_t)b_k8 * DD;

  v4f acc[4][4];
  #pragma unroll
  for (int i = 0; i < 4; ++i)
    #pragma unroll
    for (int j = 0; j < 4; ++j) acc[i][j] = (v4f){0.f, 0.f, 0.f, 0.f};

  for (int kt = 0; kt < FF / BK; ++kt) {
    #pragma unroll
    for (int g = 0; g < 4; ++g) {
      v8s h = *(const v8s*)(ha + (size_t)g * 32 * FF + kt * BK);
      *(v8s*)((char*)sA + SWZ(a_row0 + g * 32, a_kc * 2)) = h;
    }
    {
      const float* p = wb + (size_t)kt * BK * DD;
      v4f r[8];
      #pragma unroll
      for (int j = 0; j < 8; ++j) r[j] = *(const v4f*)(p + (size_t)j * DD);
      #pragma unroll
      for (int c = 0; c < 4; ++c) {
        v8s h;
        #pragma unroll
        for (int j = 0; j < 8; ++j) h[j] = f2bf(r[j][c]);
        *(v8s*)((char*)sB + SWZ(b_f4 + c, b_k8 * 2)) = h;
      }
    }
    __syncthreads();
    #pragma unroll
    for (int ks = 0; ks < 2; ++ks) {
      const int kb = ks * 64 + lg * 16;
      v8s a[4], b[4];
      #pragma unroll
      for (int m = 0; m < 4; ++m)
        a[m] = *(const v8s*)((const char*)sA + SWZ(wm + m * 16 + lr, kb));
      #pragma unroll
      for (int n = 0; n < 4; ++n)
        b[n] = *(const v8s*)((const char*)sB + SWZ(wn + n * 16 + lr, kb));
      #pragma unroll
      for (int m = 0; m < 4; ++m)
        #pragma unroll
        for (int n = 0; n < 4; ++n)
          acc[m][n] = __builtin_amdgcn_mfma_f32_16x16x32_bf16(a[m], b[n], acc[m][n], 0, 0, 0);
    }
    __syncthreads();
  }
  #pragma unroll
  for (int m = 0; m < 4; ++m)
    #pragma unroll
    for (int r = 0; r < 4; ++r) {
      int row = m0 + wm + m * 16 + lg * 4 + r;
      float wgt = wts[row];
      if (wgt != 0.f) {   // skip zero-weight padding rows (exact 0 from memset)
        float* orow = out + (size_t)ids[row] * DD + n0 + wn + lr;
        #pragma unroll
        for (int n = 0; n < 4; ++n)
          atomicAdd(orow + n * 16, wgt * acc[m][n][r]);
      }
    }
}

extern "C" void kernel_launch(void* const* d_in, const int* in_sizes, int n_in,
                              void* d_out, int out_size, void* d_ws, size_t ws_size,
                              hipStream_t stream) {
  const float* x  = (const float*)d_in[0];
  const float* gw = (const float*)d_in[1];
  const float* w1 = (const float*)d_in[2];
  const float* w3 = (const float*)d_in[3];
  const float* w2 = (const float*)d_in[4];
  float* out = (float*)d_out;
  char* ws = (char*)d_ws;

  int*   counts = (int*)(ws + WS_COUNTS);
  int*   fill   = (int*)(ws + WS_FILL);
  int*   rowoff = (int*)(ws + WS_ROWOFF);
  int*   tope   = (int*)(ws + WS_TOPE);
  float* topw   = (float*)(ws + WS_TOPW);
  int*   ids    = (int*)(ws + WS_IDS);
  float* wts    = (float*)(ws + WS_WTS);
  unsigned short* H = (unsigned short*)(ws + WS_H);

  hipMemsetAsync(ws, 0, WS_ZERO, stream);
  hipMemsetAsync(d_out, 0, (size_t)out_size * sizeof(float), stream);

  router_k<<<T_TOK / 4, 256, 0, stream>>>(x, gw, counts, tope, topw);
  offsets_k<<<1, 64, 0, stream>>>(counts, rowoff);
  scatter_k<<<T_TOK / 256, 256, 0, stream>>>(tope, topw, rowoff, fill, ids, wts);
  gemm1_k<<<dim3(FF / BN, MT_MAX), 256, 0, stream>>>(x, w1, w3, counts, rowoff, ids, H);
  gemm2_k<<<dim3(DD / BN, MT_MAX), 256, 0, stream>>>(H, w2, counts, rowoff, ids, wts, out);
}